// Round 9
// baseline (113.511 us; speedup 1.0000x reference)
//
#include <hip/hip_runtime.h>

#define TOKENS 8192
#define EXPERTS 64
#define HIDDEN 4096
#define SPLIT 16                 // K-segments (grid dimension)
#define KSEG (HIDDEN / SPLIT)    // 256 k per block
#define NS (KSEG / 32)           // 8 K-steps of 32
#define BM 128                   // tokens per block

typedef __attribute__((ext_vector_type(8))) short bf16x8;
typedef __attribute__((ext_vector_type(4))) float f32x4;

__device__ __forceinline__ unsigned short bf16_rne(float f) {
    unsigned u = __float_as_uint(f);
    return (unsigned short)((u + 0x7FFFu + ((u >> 16) & 1u)) >> 16);
}

// split 8 x f32 -> hi (RNE) + lo (trunc) bf16x8
__device__ __forceinline__ void split8(const float4& f0, const float4& f1,
                                       bf16x8& h, bf16x8& l) {
    const float fv[8] = {f0.x, f0.y, f0.z, f0.w, f1.x, f1.y, f1.z, f1.w};
#pragma unroll
    for (int j = 0; j < 8; ++j) {
        const unsigned u = __float_as_uint(fv[j]);
        const unsigned hb = (u + 0x7FFFu + ((u >> 16) & 1u)) >> 16;
        const float hf = __uint_as_float(hb << 16);
        h[j] = (short)hb;
        l[j] = (short)(__float_as_uint(fv[j] - hf) >> 16);
    }
}

// ---------------------------------------------------------------------------
// Kernel A: split w (f32) into hi/lo bf16 planes, row-major [e][k]
// ---------------------------------------------------------------------------
__global__ void prep_w(const float* __restrict__ w,
                       unsigned short* __restrict__ wh,
                       unsigned short* __restrict__ wl) {
    const int i = blockIdx.x * 256 + threadIdx.x;
    const float f = w[i];
    const unsigned short hb = bf16_rne(f);
    const float hf = __uint_as_float(((unsigned)hb) << 16);
    wh[i] = hb;
    wl[i] = bf16_rne(f - hf);
}

// ---------------------------------------------------------------------------
// zero_flags: replaces in-graph hipMemsetAsync (which cost ~75us as a graph
// memset node per replay — round 8 finding). Runs after gemm (flags overlay
// the then-dead whb region).
// ---------------------------------------------------------------------------
__global__ void zero_flags(int* __restrict__ flag_cnt) {
    if (threadIdx.x == 0 && blockIdx.x == 0) flag_cnt[0] = 0;
}

// ---------------------------------------------------------------------------
// Kernel B: barrier-free K-loop GEMM partial.
// Grid = 64 token-groups x 16 K-segments = 1024 blocks, 256 thr / 4 waves.
// B panel (hi+lo, 64x256 bf16 each) resident in 64 KB LDS, staged once with
// 16B-slot XOR swizzle. A: all 8 K-steps prefetched to regs before the single
// barrier. Inner loop: split8 + swizzled ds_read_b128 + 24 MFMA, no barriers.
// Wave w owns token rows [w*32, w*32+32) (2 M-frags); partials -> [t][s][e].
// ---------------------------------------------------------------------------
__global__ __launch_bounds__(256, 2)
void gemm_partial(const float* __restrict__ x,
                  const unsigned short* __restrict__ whb,
                  const unsigned short* __restrict__ wlb,
                  float* __restrict__ part) {
    __shared__ unsigned short Bs[2][EXPERTS][KSEG];   // 65536 B
    const int tid = threadIdx.x;
    const int w = tid >> 6;
    const int lane = tid & 63;
    const int g = lane >> 4;              // k-octet
    const int c = lane & 15;              // row (A) / col (B) within frag
    const int t0 = (blockIdx.x / SPLIT) * BM;
    const int ks0 = blockIdx.x % SPLIT;
    const int k0 = ks0 * KSEG;

    // ---- stage B panel once (swizzled 16B slots) ----
    {
        const int row = tid >> 2;         // 64 rows, 4 threads/row
        const int s0 = tid & 3;
        const int sw = (row & 7) << 4;
        const char* gh = (const char*)(whb + (size_t)row * HIDDEN + k0);
        const char* gl = (const char*)(wlb + (size_t)row * HIDDEN + k0);
        char* dh = (char*)&Bs[0][row][0];
        char* dl = (char*)&Bs[1][row][0];
#pragma unroll
        for (int j = 0; j < 8; ++j) {
            const int o = (s0 + 4 * j) * 16;          // 32 slots of 16B per row
            *(uint4*)(dh + (o ^ sw)) = *(const uint4*)(gh + o);
            *(uint4*)(dl + (o ^ sw)) = *(const uint4*)(gl + o);
        }
    }

    // ---- A: full-depth register prefetch (8 steps x 2 m-frags x 32B) ----
    const float* xa0 = x + (size_t)(t0 + w * 32 + c) * HIDDEN + k0 + g * 8;
    const float* xa1 = xa0 + (size_t)16 * HIDDEN;
    float4 ra[NS][2][2];
#pragma unroll
    for (int d = 0; d < NS; ++d) {
        ra[d][0][0] = *(const float4*)(xa0 + d * 32);
        ra[d][0][1] = *(const float4*)(xa0 + d * 32 + 4);
        ra[d][1][0] = *(const float4*)(xa1 + d * 32);
        ra[d][1][1] = *(const float4*)(xa1 + d * 32 + 4);
    }

    f32x4 acc[2][4];
#pragma unroll
    for (int m = 0; m < 2; ++m)
#pragma unroll
        for (int n = 0; n < 4; ++n) acc[m][n] = (f32x4)0.0f;

    __syncthreads();

    // ---- barrier-free K-loop ----
#pragma unroll
    for (int ks = 0; ks < NS; ++ks) {
        bf16x8 ah[2], al[2];
#pragma unroll
        for (int m = 0; m < 2; ++m)
            split8(ra[ks][m][0], ra[ks][m][1], ah[m], al[m]);
#pragma unroll
        for (int n = 0; n < 4; ++n) {
            const int r = n * 16 + c;
            const int o = (ks * 64 + g * 16) ^ ((r & 7) << 4);
            const bf16x8 bh = *(const bf16x8*)((const char*)&Bs[0][r][0] + o);
            const bf16x8 bl = *(const bf16x8*)((const char*)&Bs[1][r][0] + o);
#pragma unroll
            for (int m = 0; m < 2; ++m) {
                acc[m][n] = __builtin_amdgcn_mfma_f32_16x16x32_bf16(ah[m], bh, acc[m][n], 0, 0, 0);
                acc[m][n] = __builtin_amdgcn_mfma_f32_16x16x32_bf16(ah[m], bl, acc[m][n], 0, 0, 0);
                acc[m][n] = __builtin_amdgcn_mfma_f32_16x16x32_bf16(al[m], bh, acc[m][n], 0, 0, 0);
            }
        }
    }

    // ---- partial write: part[t][s][e]; C layout col=lane&15, row=g*4+r ----
#pragma unroll
    for (int m = 0; m < 2; ++m)
#pragma unroll
        for (int rr = 0; rr < 4; ++rr) {
            const int trow = t0 + w * 32 + m * 16 + g * 4 + rr;
            float* pb = part + ((size_t)trow * SPLIT + ks0) * EXPERTS;
#pragma unroll
            for (int n = 0; n < 4; ++n)
                pb[n * 16 + c] = acc[m][n][rr];
        }
}

// ---------------------------------------------------------------------------
// Kernel C: reduce partials -> softmax -> top-9 -> outputs + near-tie flags.
// One wave per token; lane = expert. Tie-break: lower index (lax.top_k).
// ---------------------------------------------------------------------------
__global__ __launch_bounds__(256)
void reduce_topk_kernel(const float* __restrict__ part,
                        float* __restrict__ out,
                        int* __restrict__ flag_cnt,
                        int* __restrict__ flag_list) {
    const int wid = threadIdx.x >> 6;
    const int lane = threadIdx.x & 63;
    const int t = blockIdx.x * 4 + wid;

    float logit = 0.0f;
#pragma unroll
    for (int s = 0; s < SPLIT; ++s)
        logit += part[((size_t)t * SPLIT + s) * EXPERTS + lane];

    float m = logit;
#pragma unroll
    for (int off = 32; off >= 1; off >>= 1) m = fmaxf(m, __shfl_xor(m, off, 64));
    const float ex = __expf(logit - m);
    float sum = ex;
#pragma unroll
    for (int off = 32; off >= 1; off >>= 1) sum += __shfl_xor(sum, off, 64);
    const float score = ex / sum;

    float v = score;
    bool sel = false;
    float v8 = 0.f, v9 = 0.f;
#pragma unroll
    for (int it = 0; it < 9; ++it) {
        float bv = v;
        int bi = lane;
#pragma unroll
        for (int off = 32; off >= 1; off >>= 1) {
            const float ov = __shfl_xor(bv, off, 64);
            const int oi = __shfl_xor(bi, off, 64);
            if (ov > bv || (ov == bv && oi < bi)) { bv = ov; bi = oi; }
        }
        if (it < 8) {
            if (lane == bi) { sel = true; v = -1.0f; }
            if (it == 7) v8 = bv;
        } else {
            v9 = bv;
        }
    }
    if (lane == 0 && (v8 - v9) < v8 * 1e-3f) {
        const int idx = atomicAdd(flag_cnt, 1);
        flag_list[idx] = t;
    }
    out[(size_t)t * EXPERTS + lane] = sel ? score : 0.f;
    out[(size_t)TOKENS * EXPERTS + (size_t)t * EXPERTS + lane] = sel ? 1.f : 0.f;
}

// ---------------------------------------------------------------------------
// Rescue: exact f32 recompute of flagged tokens (near-tie at rank 8/9).
// ---------------------------------------------------------------------------
__global__ __launch_bounds__(256)
void router_rescue(const float* __restrict__ x, const float* __restrict__ wgt,
                   float* __restrict__ out, const int* __restrict__ cnt,
                   const int* __restrict__ list) {
    __shared__ float xrow[HIDDEN];
    __shared__ float lg[EXPERTS];
    const int tid = threadIdx.x;
    const int w = tid >> 6, lane = tid & 63;
    const int n = cnt[0];
    for (int i = blockIdx.x; i < n; i += 256) {
        const int t = list[i];
        __syncthreads();
        for (int j = tid; j < HIDDEN / 4; j += 256)
            ((float4*)xrow)[j] = ((const float4*)(x + (size_t)t * HIDDEN))[j];
        __syncthreads();
#pragma unroll 2
        for (int ei = 0; ei < 16; ++ei) {
            const int e = w * 16 + ei;
            const float* wr = wgt + (size_t)e * HIDDEN;
            float a = 0.f;
            for (int kk = 0; kk < HIDDEN; kk += 256) {
                const float4 xv = *(const float4*)(xrow + kk + lane * 4);
                const float4 wv = *(const float4*)(wr + kk + lane * 4);
                a = fmaf(xv.x, wv.x, a); a = fmaf(xv.y, wv.y, a);
                a = fmaf(xv.z, wv.z, a); a = fmaf(xv.w, wv.w, a);
            }
#pragma unroll
            for (int off = 32; off >= 1; off >>= 1) a += __shfl_xor(a, off, 64);
            if (lane == 0) lg[e] = a;
        }
        __syncthreads();
        if (w == 0) {
            const float logit = lg[lane];
            float m = logit;
#pragma unroll
            for (int off = 32; off >= 1; off >>= 1) m = fmaxf(m, __shfl_xor(m, off, 64));
            const float ex = __expf(logit - m);
            float sum = ex;
#pragma unroll
            for (int off = 32; off >= 1; off >>= 1) sum += __shfl_xor(sum, off, 64);
            const float score = ex / sum;
            float v = score;
            bool sel = false;
#pragma unroll
            for (int it = 0; it < 8; ++it) {
                float bv = v; int bi = lane;
#pragma unroll
                for (int off = 32; off >= 1; off >>= 1) {
                    const float ov = __shfl_xor(bv, off, 64);
                    const int oi = __shfl_xor(bi, off, 64);
                    if (ov > bv || (ov == bv && oi < bi)) { bv = ov; bi = oi; }
                }
                if (lane == bi) { sel = true; v = -1.f; }
            }
            out[(size_t)t * EXPERTS + lane] = sel ? score : 0.f;
            out[(size_t)TOKENS * EXPERTS + (size_t)t * EXPERTS + lane] = sel ? 1.f : 0.f;
        }
        __syncthreads();
    }
}

// ---------------------------------------------------------------------------
extern "C" void kernel_launch(void* const* d_in, const int* in_sizes, int n_in,
                              void* d_out, int out_size, void* d_ws, size_t ws_size,
                              hipStream_t stream) {
    (void)in_sizes; (void)n_in; (void)out_size; (void)ws_size;
    const float* x = (const float*)d_in[0];       // [8192][4096] f32
    const float* w = (const float*)d_in[1];       // [64][4096] f32
    float* out = (float*)d_out;

    // ws layout: whb 0..512K, wlb 512K..1M, part 1M..33M ([t][s][e] f32).
    // flags overlay the (dead-after-gemm) whb region; zeroed by a micro-kernel
    // AFTER gemm (in-graph hipMemsetAsync costs ~75us/replay — round 8).
    unsigned short* whb = (unsigned short*)d_ws;
    unsigned short* wlb = (unsigned short*)((char*)d_ws + (512 << 10));
    float* part = (float*)((char*)d_ws + (1 << 20));
    int* flag_cnt = (int*)d_ws;
    int* flag_list = (int*)((char*)d_ws + 256);

    prep_w<<<(EXPERTS * HIDDEN) / 256, 256, 0, stream>>>(w, whb, wlb);
    gemm_partial<<<(TOKENS / BM) * SPLIT, 256, 0, stream>>>(x, whb, wlb, part);
    zero_flags<<<1, 64, 0, stream>>>(flag_cnt);
    reduce_topk_kernel<<<TOKENS / 4, 256, 0, stream>>>(part, out, flag_cnt, flag_list);
    router_rescue<<<256, 256, 0, stream>>>(x, w, out, flag_cnt, flag_list);
}

// Round 10
// 105.948 us; speedup vs baseline: 1.0714x; 1.0714x over previous
//
#include <hip/hip_runtime.h>

#define TOKENS 8192
#define EXPERTS 64
#define HIDDEN 4096
#define KSPLIT 8                 // K-segments (grid dim)
#define KSEG (HIDDEN / KSPLIT)   // 512 k per block
#define CH 64                    // k per chunk
#define NCH (KSEG / CH)          // 8 chunks
#define BM 64                    // tokens per block

typedef __attribute__((ext_vector_type(8))) short bf16x8;
typedef __attribute__((ext_vector_type(4))) float f32x4;

__device__ __forceinline__ unsigned short bf16_rne(float f) {
    unsigned u = __float_as_uint(f);
    return (unsigned short)((u + 0x7FFFu + ((u >> 16) & 1u)) >> 16);
}

// split 8 x f32 -> hi (RNE) + lo (trunc) bf16x8
__device__ __forceinline__ void split8(const float4& f0, const float4& f1,
                                       bf16x8& h, bf16x8& l) {
    const float fv[8] = {f0.x, f0.y, f0.z, f0.w, f1.x, f1.y, f1.z, f1.w};
#pragma unroll
    for (int j = 0; j < 8; ++j) {
        const unsigned u = __float_as_uint(fv[j]);
        const unsigned hb = (u + 0x7FFFu + ((u >> 16) & 1u)) >> 16;
        const float hf = __uint_as_float(hb << 16);
        h[j] = (short)hb;
        l[j] = (short)(__float_as_uint(fv[j] - hf) >> 16);
    }
}

// ---------------------------------------------------------------------------
// Kernel A: split w into hi/lo bf16 planes; thread 0 also zeroes flag_cnt.
// ---------------------------------------------------------------------------
__global__ void prep_w(const float* __restrict__ w,
                       unsigned short* __restrict__ wh,
                       unsigned short* __restrict__ wl,
                       int* __restrict__ flag_cnt) {
    const int i = blockIdx.x * 256 + threadIdx.x;
    if (i == 0) flag_cnt[0] = 0;
    const float f = w[i];
    const unsigned short hb = bf16_rne(f);
    const float hf = __uint_as_float(((unsigned)hb) << 16);
    wh[i] = hb;
    wl[i] = bf16_rne(f - hf);
}

// ---------------------------------------------------------------------------
// Kernel B: streaming GEMM partial, high-TLP variant.
// Grid = 128 token-groups x 8 K-segments = 1024 blocks (4/CU), 256 thr/4 waves.
// Wave w owns tokens [t0+w*16, +16) (1 M-frag); N=64 (4 frags); K=512 per
// block in 8 chunks of 64. B chunk (hi+lo) dbuf'd in 32 KB LDS with
// (row&7)<<4 slot swizzle; A chunk in regs (4 float4, parity-dbuf'd).
// One barrier per chunk; next chunk's loads issued AFTER the barrier so they
// drain one full compute phase later. Target <=128 VGPR -> 16 waves/CU.
// ---------------------------------------------------------------------------
__global__ __launch_bounds__(256, 4)
void gemm_partial(const float* __restrict__ x,
                  const unsigned short* __restrict__ whb,
                  const unsigned short* __restrict__ wlb,
                  float* __restrict__ part) {
    __shared__ unsigned short Bs[2][2][EXPERTS][CH];   // 32 KB
    const int tid = threadIdx.x;
    const int w = tid >> 6;
    const int lane = tid & 63;
    const int g = lane >> 4;              // k-octet
    const int c = lane & 15;              // token row (A) / expert col (B)
    const int t0 = (blockIdx.x >> 3) * BM;
    const int ks0 = blockIdx.x & 7;
    const int k0 = ks0 * KSEG;

    // ---- B staging geometry: 4 threads per expert row ----
    const int brow = tid >> 2;            // 0..63
    const int qi = tid & 3;
    const int sw = (brow & 7) << 4;
    const int o0 = (qi * 32) ^ sw;        // two 16B slots per thread per plane
    const int o1 = (qi * 32 + 16) ^ sw;
    const unsigned short* gbh = whb + (size_t)brow * HIDDEN + k0 + qi * 16;
    const unsigned short* gbl = wlb + (size_t)brow * HIDDEN + k0 + qi * 16;
    char* const dh0 = (char*)&Bs[0][0][brow][0];
    char* const dl0 = (char*)&Bs[0][1][brow][0];
    char* const dh1 = (char*)&Bs[1][0][brow][0];
    char* const dl1 = (char*)&Bs[1][1][brow][0];

    // ---- A geometry: lane (g,c) of wave w reads its own MFMA fragment ----
    const float* xa = x + (size_t)(t0 + w * 16 + c) * HIDDEN + k0 + g * 8;

    uint4 rbh0, rbh1, rbl0, rbl1;
    float4 raA[4], raB[4];

#define BLOAD(ch)                                                        \
    do {                                                                 \
        const int _o = (ch) * CH;                                        \
        rbh0 = *(const uint4*)(gbh + _o);                                \
        rbh1 = *(const uint4*)(gbh + _o + 8);                            \
        rbl0 = *(const uint4*)(gbl + _o);                                \
        rbl1 = *(const uint4*)(gbl + _o + 8);                            \
    } while (0)

#define BWRITE0()                                                        \
    do {                                                                 \
        *(uint4*)(dh0 + o0) = rbh0; *(uint4*)(dh0 + o1) = rbh1;          \
        *(uint4*)(dl0 + o0) = rbl0; *(uint4*)(dl0 + o1) = rbl1;          \
    } while (0)
#define BWRITE1()                                                        \
    do {                                                                 \
        *(uint4*)(dh1 + o0) = rbh0; *(uint4*)(dh1 + o1) = rbh1;          \
        *(uint4*)(dl1 + o0) = rbl0; *(uint4*)(dl1 + o1) = rbl1;          \
    } while (0)

#define ALOAD(ra, ch)                                                    \
    do {                                                                 \
        const float* _p = xa + (ch) * CH;                                \
        ra[0] = *(const float4*)(_p);                                    \
        ra[1] = *(const float4*)(_p + 4);                                \
        ra[2] = *(const float4*)(_p + 32);                               \
        ra[3] = *(const float4*)(_p + 36);                               \
    } while (0)

    f32x4 acc[4];
#pragma unroll
    for (int n = 0; n < 4; ++n) acc[n] = (f32x4)0.0f;

#define COMPUTE(buf, ra)                                                 \
    do {                                                                 \
        _Pragma("unroll")                                                \
        for (int s = 0; s < 2; ++s) {                                    \
            bf16x8 ah, al;                                               \
            split8(ra[s * 2], ra[s * 2 + 1], ah, al);                    \
            _Pragma("unroll")                                            \
            for (int n = 0; n < 4; ++n) {                                \
                const int r = n * 16 + c;                                \
                const int o = (s * 64 + g * 16) ^ ((r & 7) << 4);        \
                const bf16x8 bh =                                        \
                    *(const bf16x8*)((const char*)&Bs[buf][0][r][0] + o);\
                const bf16x8 bl =                                        \
                    *(const bf16x8*)((const char*)&Bs[buf][1][r][0] + o);\
                acc[n] = __builtin_amdgcn_mfma_f32_16x16x32_bf16(        \
                    ah, bh, acc[n], 0, 0, 0);                            \
                acc[n] = __builtin_amdgcn_mfma_f32_16x16x32_bf16(        \
                    ah, bl, acc[n], 0, 0, 0);                            \
                acc[n] = __builtin_amdgcn_mfma_f32_16x16x32_bf16(        \
                    al, bh, acc[n], 0, 0, 0);                            \
            }                                                            \
        }                                                                \
    } while (0)

    // ---- pipeline: 1 barrier/chunk; loads for ch+1 issued after barrier ----
    BLOAD(0); ALOAD(raA, 0);
    BWRITE0();
    __syncthreads();
    BLOAD(1); ALOAD(raB, 1);
    COMPUTE(0, raA);

    for (int i = 1; i < NCH; i += 2) {
        BWRITE1();
        __syncthreads();
        if (i + 1 < NCH) { BLOAD(i + 1); ALOAD(raA, i + 1); }
        COMPUTE(1, raB);
        if (i + 1 < NCH) {
            BWRITE0();
            __syncthreads();
            if (i + 2 < NCH) { BLOAD(i + 2); ALOAD(raB, i + 2); }
            COMPUTE(0, raA);
        }
    }
#undef BLOAD
#undef BWRITE0
#undef BWRITE1
#undef ALOAD
#undef COMPUTE

    // ---- partial write: part[t][ks][e]; C layout col=lane&15, row=g*4+r ----
#pragma unroll
    for (int rr = 0; rr < 4; ++rr) {
        const int trow = t0 + w * 16 + g * 4 + rr;
        float* pb = part + ((size_t)trow * KSPLIT + ks0) * EXPERTS;
#pragma unroll
        for (int n = 0; n < 4; ++n)
            pb[n * 16 + c] = acc[n][rr];
    }
}

// ---------------------------------------------------------------------------
// Kernel C: reduce partials -> softmax -> top-9 -> outputs + near-tie flags.
// One wave per token; lane = expert. Tie-break: lower index (lax.top_k).
// ---------------------------------------------------------------------------
__global__ __launch_bounds__(256)
void reduce_topk_kernel(const float* __restrict__ part,
                        float* __restrict__ out,
                        int* __restrict__ flag_cnt,
                        int* __restrict__ flag_list) {
    const int wid = threadIdx.x >> 6;
    const int lane = threadIdx.x & 63;
    const int t = blockIdx.x * 4 + wid;

    float logit = 0.0f;
#pragma unroll
    for (int s = 0; s < KSPLIT; ++s)
        logit += part[((size_t)t * KSPLIT + s) * EXPERTS + lane];

    float m = logit;
#pragma unroll
    for (int off = 32; off >= 1; off >>= 1) m = fmaxf(m, __shfl_xor(m, off, 64));
    const float ex = __expf(logit - m);
    float sum = ex;
#pragma unroll
    for (int off = 32; off >= 1; off >>= 1) sum += __shfl_xor(sum, off, 64);
    const float score = ex / sum;

    float v = score;
    bool sel = false;
    float v8 = 0.f, v9 = 0.f;
#pragma unroll
    for (int it = 0; it < 9; ++it) {
        float bv = v;
        int bi = lane;
#pragma unroll
        for (int off = 32; off >= 1; off >>= 1) {
            const float ov = __shfl_xor(bv, off, 64);
            const int oi = __shfl_xor(bi, off, 64);
            if (ov > bv || (ov == bv && oi < bi)) { bv = ov; bi = oi; }
        }
        if (it < 8) {
            if (lane == bi) { sel = true; v = -1.0f; }
            if (it == 7) v8 = bv;
        } else {
            v9 = bv;
        }
    }
    if (lane == 0 && (v8 - v9) < v8 * 1e-3f) {
        const int idx = atomicAdd(flag_cnt, 1);
        flag_list[idx] = t;
    }
    out[(size_t)t * EXPERTS + lane] = sel ? score : 0.f;
    out[(size_t)TOKENS * EXPERTS + (size_t)t * EXPERTS + lane] = sel ? 1.f : 0.f;
}

// ---------------------------------------------------------------------------
// Rescue: exact f32 recompute of flagged tokens (near-tie at rank 8/9).
// ---------------------------------------------------------------------------
__global__ __launch_bounds__(256)
void router_rescue(const float* __restrict__ x, const float* __restrict__ wgt,
                   float* __restrict__ out, const int* __restrict__ cnt,
                   const int* __restrict__ list) {
    __shared__ float xrow[HIDDEN];
    __shared__ float lg[EXPERTS];
    const int tid = threadIdx.x;
    const int w = tid >> 6, lane = tid & 63;
    const int n = cnt[0];
    for (int i = blockIdx.x; i < n; i += 256) {
        const int t = list[i];
        __syncthreads();
        for (int j = tid; j < HIDDEN / 4; j += 256)
            ((float4*)xrow)[j] = ((const float4*)(x + (size_t)t * HIDDEN))[j];
        __syncthreads();
#pragma unroll 2
        for (int ei = 0; ei < 16; ++ei) {
            const int e = w * 16 + ei;
            const float* wr = wgt + (size_t)e * HIDDEN;
            float a = 0.f;
            for (int kk = 0; kk < HIDDEN; kk += 256) {
                const float4 xv = *(const float4*)(xrow + kk + lane * 4);
                const float4 wv = *(const float4*)(wr + kk + lane * 4);
                a = fmaf(xv.x, wv.x, a); a = fmaf(xv.y, wv.y, a);
                a = fmaf(xv.z, wv.z, a); a = fmaf(xv.w, wv.w, a);
            }
#pragma unroll
            for (int off = 32; off >= 1; off >>= 1) a += __shfl_xor(a, off, 64);
            if (lane == 0) lg[e] = a;
        }
        __syncthreads();
        if (w == 0) {
            const float logit = lg[lane];
            float m = logit;
#pragma unroll
            for (int off = 32; off >= 1; off >>= 1) m = fmaxf(m, __shfl_xor(m, off, 64));
            const float ex = __expf(logit - m);
            float sum = ex;
#pragma unroll
            for (int off = 32; off >= 1; off >>= 1) sum += __shfl_xor(sum, off, 64);
            const float score = ex / sum;
            float v = score;
            bool sel = false;
#pragma unroll
            for (int it = 0; it < 8; ++it) {
                float bv = v; int bi = lane;
#pragma unroll
                for (int off = 32; off >= 1; off >>= 1) {
                    const float ov = __shfl_xor(bv, off, 64);
                    const int oi = __shfl_xor(bi, off, 64);
                    if (ov > bv || (ov == bv && oi < bi)) { bv = ov; bi = oi; }
                }
                if (lane == bi) { sel = true; v = -1.f; }
            }
            out[(size_t)t * EXPERTS + lane] = sel ? score : 0.f;
            out[(size_t)TOKENS * EXPERTS + (size_t)t * EXPERTS + lane] = sel ? 1.f : 0.f;
        }
        __syncthreads();
    }
}

// ---------------------------------------------------------------------------
extern "C" void kernel_launch(void* const* d_in, const int* in_sizes, int n_in,
                              void* d_out, int out_size, void* d_ws, size_t ws_size,
                              hipStream_t stream) {
    (void)in_sizes; (void)n_in; (void)out_size; (void)ws_size;
    const float* x = (const float*)d_in[0];       // [8192][4096] f32
    const float* w = (const float*)d_in[1];       // [64][4096] f32
    float* out = (float*)d_out;

    // ws: whb [0,512K) | wlb [512K,1M) | part [1M,17M) | flags [17M,..)
    unsigned short* whb = (unsigned short*)d_ws;
    unsigned short* wlb = (unsigned short*)((char*)d_ws + (512 << 10));
    float* part = (float*)((char*)d_ws + (1 << 20));
    int* flag_cnt = (int*)((char*)d_ws + (17 << 20));
    int* flag_list = (int*)((char*)d_ws + (17 << 20) + 256);

    prep_w<<<(EXPERTS * HIDDEN) / 256, 256, 0, stream>>>(w, whb, wlb, flag_cnt);
    gemm_partial<<<(TOKENS / BM) * KSPLIT, 256, 0, stream>>>(x, whb, wlb, part);
    reduce_topk_kernel<<<TOKENS / 4, 256, 0, stream>>>(part, out, flag_cnt, flag_list);
    router_rescue<<<256, 256, 0, stream>>>(x, w, out, flag_cnt, flag_list);
}